// Round 9
// baseline (188.864 us; speedup 1.0000x reference)
//
#include <hip/hip_runtime.h>
#include <hip/hip_bf16.h>
#include <stdint.h>
#include <stddef.h>

#define B_N 4
#define S_N 2048
#define D_N 1024
#define H_N 16
#define HD_N 64

typedef __bf16 bf16;
typedef __bf16 bf16x8 __attribute__((ext_vector_type(8)));
typedef __bf16 bf16x4 __attribute__((ext_vector_type(4)));
typedef float f32x4 __attribute__((ext_vector_type(4)));

__device__ __forceinline__ void gload_lds16(const void* g, void* l) {
  __builtin_amdgcn_global_load_lds((const __attribute__((address_space(1))) void*)g,
                                   (__attribute__((address_space(3))) void*)l,
                                   16, 0, 0);
}

__global__ __launch_bounds__(256) void cvt_f32_bf16(const float* __restrict__ in,
                                                    bf16* __restrict__ out, int n4) {
  int i = blockIdx.x * blockDim.x + threadIdx.x;
  const int stride = gridDim.x * blockDim.x;
  for (; i < n4; i += stride) {
    const float4 v = ((const float4*)in)[i];
    bf16x4 o;
    o[0] = (bf16)v.x; o[1] = (bf16)v.y; o[2] = (bf16)v.z; o[3] = (bf16)v.w;
    ((bf16x4*)out)[i] = o;
  }
}

// all four 1024x1024 weights in one dispatch (512 blocks each)
__global__ __launch_bounds__(256) void cvt_w4(const float* __restrict__ w0,
                                              const float* __restrict__ w1,
                                              const float* __restrict__ w2,
                                              const float* __restrict__ w3,
                                              bf16* __restrict__ o0, bf16* __restrict__ o1,
                                              bf16* __restrict__ o2, bf16* __restrict__ o3) {
  const int n4 = (D_N * D_N) / 4;
  const int which = blockIdx.x >> 9;
  const float* in = which == 0 ? w0 : which == 1 ? w1 : which == 2 ? w2 : w3;
  bf16* out = which == 0 ? o0 : which == 1 ? o1 : which == 2 ? o2 : o3;
  int i = (blockIdx.x & 511) * 256 + threadIdx.x;
  const int stride = 512 * 256;
  for (; i < n4; i += stride) {
    const float4 v = ((const float4*)in)[i];
    bf16x4 o;
    o[0] = (bf16)v.x; o[1] = (bf16)v.y; o[2] = (bf16)v.z; o[3] = (bf16)v.w;
    ((bf16x4*)out)[i] = o;
  }
}

// ---- GEMM body: C = A(8192x1024) * W(1024x1024)^T + bias ----
// 512 threads (8 waves, 4M x 2N of 64x64), BM=256 BN=128 BK=64.
// 3-buffer LDS (144KB), stage lead = 2 K-tiles, counted vmcnt(6) (T3+T4),
// XOR-swizzled LDS rows (T2, rule-21 involution), setprio on MFMA (T5),
// ONE raw barrier per K-tile.
template <typename OutFn>
__device__ __forceinline__ void gemm_body(const bf16* __restrict__ A,
                                          const bf16* __restrict__ W, int m0, int n0,
                                          bf16* sAq, bf16* sBq, OutFn&& emit) {
  const int tid = threadIdx.x;
  const int wave = tid >> 6;
  const int lane = tid & 63;
  const int l16 = lane & 15;
  const int lhi = lane >> 4;
  const int wm = (wave >> 1) * 64;  // 4 M-groups of 64
  const int wn = (wave & 1) * 64;   // 2 N-groups of 64
  // staging: dest row (within 64-row group) = wave*8 + lane>>3, dest chunk = lane&7,
  // source chunk pre-swizzled: c ^ (row&7) with row&7 == lane>>3
  const int srow = wave * 8 + (lane >> 3);
  const int scol = 8 * ((lane & 7) ^ (lane >> 3));  // elems
  const int sdst = wave * 8 * 64;                   // elems; +q*4096; HW adds lane*16B
  // read swizzle: chunk' = (kk*4 + lhi) ^ (row&7), row&7 == l16&7 (bases are 16-mult)
  const int aoff0 = (lhi ^ (l16 & 7)) * 8;          // elems; kk=1 -> ^32

  f32x4 acc[4][4];
#pragma unroll
  for (int i = 0; i < 4; ++i)
#pragma unroll
    for (int j = 0; j < 4; ++j) acc[i][j] = (f32x4){0.f, 0.f, 0.f, 0.f};

#define SG_A(buf_, kt_)                                                                 \
  {                                                                                     \
    _Pragma("unroll") for (int q = 0; q < 4; ++q)                                       \
        gload_lds16(A + (size_t)(m0 + q * 64 + srow) * D_N + (kt_) * 64 + scol,         \
                    sAq + (buf_) * 16384 + sdst + q * 4096);                            \
  }
#define SG_B(buf_, kt_)                                                                 \
  {                                                                                     \
    _Pragma("unroll") for (int q = 0; q < 2; ++q)                                       \
        gload_lds16(W + (size_t)(n0 + q * 64 + srow) * D_N + (kt_) * 64 + scol,         \
                    sBq + (buf_) * 8192 + sdst + q * 4096);                             \
  }
#define PHASE(cur_, kk_)                                                                \
  {                                                                                     \
    const bf16* a_ = sAq + (cur_) * 16384;                                              \
    const bf16* b_ = sBq + (cur_) * 8192;                                               \
    bf16x8 af[4], bfr[4];                                                               \
    _Pragma("unroll") for (int i = 0; i < 4; ++i)                                       \
        af[i] = *(const bf16x8*)(a_ + (wm + i * 16 + l16) * 64 + (aoff0 ^ ((kk_)*32))); \
    _Pragma("unroll") for (int j = 0; j < 4; ++j)                                       \
        bfr[j] = *(const bf16x8*)(b_ + (wn + j * 16 + l16) * 64 + (aoff0 ^ ((kk_)*32)));\
    __builtin_amdgcn_s_setprio(1);                                                      \
    _Pragma("unroll") for (int i = 0; i < 4; ++i)                                       \
        _Pragma("unroll") for (int j = 0; j < 4; ++j)                                   \
            acc[i][j] = __builtin_amdgcn_mfma_f32_16x16x32_bf16(af[i], bfr[j],          \
                                                                acc[i][j], 0, 0, 0);    \
    __builtin_amdgcn_s_setprio(0);                                                      \
  }

  const int NT = D_N / 64;  // 16 K-tiles; tile u lives in buffer u%3

  // prologue: stage tiles 0,1; wait tile 0 (6 of 12 outstanding)
  SG_A(0, 0); SG_B(0, 0);
  SG_A(1, 1); SG_B(1, 1);
  asm volatile("s_waitcnt vmcnt(6)" ::: "memory");
  asm volatile("s_barrier" ::: "memory");

  for (int t = 0; t < NT - 2; ++t) {
    const int cur = t % 3, nx = (t + 2) % 3;
    SG_A(nx, t + 2);        // 4 loads into the buffer freed at end of tile t-1
    PHASE(cur, 0);
    SG_B(nx, t + 2);        // 2 loads
    PHASE(cur, 1);
    // lgkm(0): my LDS reads landed; vmcnt(6): tile t+1's 6 loads landed
    // (tile t+2's 6 stay in flight). Barrier joins -> all waves' stages visible.
    asm volatile("s_waitcnt vmcnt(6) lgkmcnt(0)" ::: "memory");
    asm volatile("s_barrier" ::: "memory");
  }
  // tile NT-2: nothing left to stage; drain tile NT-1's loads
  PHASE((NT - 2) % 3, 0);
  PHASE((NT - 2) % 3, 1);
  asm volatile("s_waitcnt vmcnt(0) lgkmcnt(0)" ::: "memory");
  asm volatile("s_barrier" ::: "memory");
  // tile NT-1
  PHASE((NT - 1) % 3, 0);
  PHASE((NT - 1) % 3, 1);

#undef SG_A
#undef SG_B
#undef PHASE

#pragma unroll
  for (int i = 0; i < 4; ++i)
#pragma unroll
    for (int j = 0; j < 4; ++j)
      emit(m0 + wm + i * 16 + lhi * 4, n0 + wn + j * 16 + l16, acc[i][j]);
}

// Fused Q/K/V projection: which = blockIdx.x>>3 selects weight/bias/output.
__global__ __launch_bounds__(512) void gemm_qkv(const bf16* __restrict__ A,
                                                const bf16* __restrict__ Wq,
                                                const bf16* __restrict__ Wk,
                                                const bf16* __restrict__ Wv,
                                                const float* __restrict__ bq,
                                                const float* __restrict__ bk,
                                                const float* __restrict__ bv,
                                                bf16* __restrict__ outQ,
                                                bf16* __restrict__ outK,
                                                bf16* __restrict__ outVt) {
  __shared__ __align__(16) bf16 sAq[3 * 256 * 64];
  __shared__ __align__(16) bf16 sBq[3 * 128 * 64];
  const int which = blockIdx.x >> 3;
  const int n0 = (blockIdx.x & 7) * 128;
  const int m0 = blockIdx.y * 256;
  const bf16* W = which == 0 ? Wq : which == 1 ? Wk : Wv;
  const float* bias = which == 0 ? bq : which == 1 ? bk : bv;

  if (which == 2) {
    gemm_body(A, W, m0, n0, sAq, sBq, [&](int row0, int col, const f32x4& a) {
      const float bvv = bias[col];
      const int b = row0 >> 11, s = row0 & (S_N - 1);
      const int h = col >> 6, hd = col & 63;
      bf16x4 pk;
#pragma unroll
      for (int r = 0; r < 4; ++r) pk[r] = (bf16)(a[r] + bvv);
      *(bf16x4*)&outVt[(((size_t)b * H_N + h) * HD_N + hd) * S_N + s] = pk;
    });
  } else {
    bf16* out = which == 0 ? outQ : outK;
    gemm_body(A, W, m0, n0, sAq, sBq, [&](int row0, int col, const f32x4& a) {
      const float bvv = bias[col];
      const int h = col >> 6, hd = col & 63;
#pragma unroll
      for (int r = 0; r < 4; ++r) {
        const int row = row0 + r;
        const int b = row >> 11, s = row & (S_N - 1);
        out[(((size_t)b * H_N + h) * S_N + s) * HD_N + hd] = (bf16)(a[r] + bvv);
      }
    });
  }
}

// O-projection: f32 output row-major
__global__ __launch_bounds__(512) void gemm_out(const bf16* __restrict__ A,
                                                const bf16* __restrict__ W,
                                                const float* __restrict__ bias,
                                                float* __restrict__ out) {
  __shared__ __align__(16) bf16 sAq[3 * 256 * 64];
  __shared__ __align__(16) bf16 sBq[3 * 128 * 64];
  const int n0 = blockIdx.x * 128;
  const int m0 = blockIdx.y * 256;
  gemm_body(A, W, m0, n0, sAq, sBq, [&](int row0, int col, const f32x4& a) {
    const float bvv = bias[col];
#pragma unroll
    for (int r = 0; r < 4; ++r) out[(size_t)(row0 + r) * D_N + col] = a[r] + bvv;
  });
}

// Causal attention (round-8 structure, unchanged). Block-shared, double-
// buffered, XOR-swizzled K/V LDS staging. Fixed-max softmax (-4 in MFMA
// C-init), exp2 domain. bh = bid&63 -> XCD-local K/V. Heavy q-tiles first.
__global__ __launch_bounds__(256, 3) void attn_fwd(const bf16* __restrict__ Q,
                                                   const bf16* __restrict__ K,
                                                   const bf16* __restrict__ Vt,
                                                   bf16* __restrict__ O) {
  __shared__ __align__(16) bf16 sK[2][64 * 64];
  __shared__ __align__(16) bf16 sV[2][64 * 64];
  __shared__ __align__(16) bf16 sP[4][32 * 72];
  const int tid = threadIdx.x;
  const int wave = tid >> 6;
  const int lane = tid & 63;
  const int l16 = lane & 15;
  const int lhi = lane >> 4;
  const int bidx = blockIdx.x;       // [0,1024)
  const int bh = bidx & 63;          // XCD = bidx%8 = bh%8 -> 8 heads/XCD (L2-fit)
  const int qt = 15 - (bidx >> 6);   // heavy q-tiles first
  const int q0 = qt * 128 + wave * 32;
  const bf16* Qh = Q + (size_t)bh * S_N * HD_N;
  const bf16* Kh = K + (size_t)bh * S_N * HD_N;
  const bf16* Vth = Vt + (size_t)bh * HD_N * S_N;
  const int b = bh >> 4, h = bh & 15;

  const int srow = lane >> 3;
  const int scol = 8 * ((lane & 7) ^ srow);

  const float QS = 0.03125f * 1.44269504088896340736f;
  const f32x4 z4 = {0.0f, 0.0f, 0.0f, 0.0f};
  const f32x4 m4 = {-4.0f, -4.0f, -4.0f, -4.0f};
  const bf16 oneb = (bf16)1.0f;
  const bf16x8 ones = {oneb, oneb, oneb, oneb, oneb, oneb, oneb, oneb};
  bf16* sPw = sP[wave];

  bf16x8 qf[2][2];
#pragma unroll
  for (int i = 0; i < 2; ++i)
#pragma unroll
    for (int kq = 0; kq < 2; ++kq) {
      const bf16x8 raw =
          *(const bf16x8*)&Qh[(size_t)(q0 + i * 16 + l16) * HD_N + kq * 32 + lhi * 8];
      bf16x8 s;
#pragma unroll
      for (int e = 0; e < 8; ++e) s[e] = (bf16)((float)raw[e] * QS);
      qf[i][kq] = s;
    }

  f32x4 o[2][4];
  f32x4 osum[2];
#pragma unroll
  for (int i = 0; i < 2; ++i) {
#pragma unroll
    for (int j = 0; j < 4; ++j) o[i][j] = z4;
    osum[i] = z4;
  }

#define STAGE(buf, kb_)                                                                  \
  {                                                                                      \
    _Pragma("unroll") for (int is = 0; is < 2; ++is) {                                   \
      const int r0 = is * 32 + wave * 8;                                                 \
      gload_lds16(Kh + (size_t)((kb_)*64 + r0 + srow) * HD_N + scol, &sK[buf][r0 * 64]); \
      gload_lds16(Vth + (size_t)(r0 + srow) * S_N + (kb_)*64 + scol, &sV[buf][r0 * 64]); \
    }                                                                                    \
  }

  const int nkb = 2 * qt + 2;

  STAGE(0, 0);
  __syncthreads();

  for (int kb = 0; kb < nkb; ++kb) {
    const int cur = kb & 1;
    if (kb + 1 < nkb) STAGE(cur ^ 1, kb + 1);
    const bf16* sKb = sK[cur];
    const bf16* sVb = sV[cur];
    const int k0 = kb * 64;

    if (k0 <= q0 + 31) {
      f32x4 sc[2][4];
#pragma unroll
      for (int i = 0; i < 2; ++i)
#pragma unroll
        for (int j = 0; j < 4; ++j) sc[i][j] = m4;
      __builtin_amdgcn_s_setprio(1);
#pragma unroll
      for (int j = 0; j < 4; ++j) {
        const int row = j * 16 + l16;
#pragma unroll
        for (int kq = 0; kq < 2; ++kq) {
          const bf16x8 kfr = *(const bf16x8*)((const char*)sKb + row * 128 +
                                              ((kq * 64 + lhi * 16) ^ ((row & 7) << 4)));
#pragma unroll
          for (int i = 0; i < 2; ++i)
            sc[i][j] = __builtin_amdgcn_mfma_f32_16x16x32_bf16(qf[i][kq], kfr, sc[i][j], 0, 0, 0);
        }
      }
      __builtin_amdgcn_s_setprio(0);

      if (k0 + 63 > q0) {
#pragma unroll
        for (int i = 0; i < 2; ++i)
#pragma unroll
          for (int r = 0; r < 4; ++r) {
            const int qrow = q0 + i * 16 + lhi * 4 + r;
#pragma unroll
            for (int j = 0; j < 4; ++j)
              if (k0 + j * 16 + l16 > qrow) sc[i][j][r] = -3e38f;
          }
      }

#pragma unroll
      for (int i = 0; i < 2; ++i)
#pragma unroll
        for (int r = 0; r < 4; ++r)
#pragma unroll
          for (int j = 0; j < 4; ++j)
            sPw[(i * 16 + lhi * 4 + r) * 72 + j * 16 + l16] = (bf16)__builtin_exp2f(sc[i][j][r]);

      __builtin_amdgcn_s_setprio(1);
#pragma unroll
      for (int kq = 0; kq < 2; ++kq) {
        bf16x8 pa[2];
#pragma unroll
        for (int i = 0; i < 2; ++i)
          pa[i] = *(const bf16x8*)&sPw[(i * 16 + l16) * 72 + kq * 32 + lhi * 8];
#pragma unroll
        for (int i = 0; i < 2; ++i)
          osum[i] = __builtin_amdgcn_mfma_f32_16x16x32_bf16(pa[i], ones, osum[i], 0, 0, 0);
#pragma unroll
        for (int jd = 0; jd < 4; ++jd) {
          const int vrow = jd * 16 + l16;
          const bf16x8 vb = *(const bf16x8*)((const char*)sVb + vrow * 128 +
                                             ((kq * 64 + lhi * 16) ^ ((vrow & 7) << 4)));
#pragma unroll
          for (int i = 0; i < 2; ++i)
            o[i][jd] = __builtin_amdgcn_mfma_f32_16x16x32_bf16(pa[i], vb, o[i][jd], 0, 0, 0);
        }
      }
      __builtin_amdgcn_s_setprio(0);
    }
    __syncthreads();
  }

#pragma unroll
  for (int i = 0; i < 2; ++i) {
#pragma unroll
    for (int r = 0; r < 4; ++r) {
      const float inv = 1.0f / osum[i][r];
      const size_t token = (size_t)b * S_N + q0 + i * 16 + lhi * 4 + r;
#pragma unroll
      for (int jd = 0; jd < 4; ++jd) {
        const int col = h * 64 + jd * 16 + l16;
        O[token * D_N + col] = (bf16)(o[i][jd][r] * inv);
      }
    }
  }
#undef STAGE
}

extern "C" void kernel_launch(void* const* d_in, const int* in_sizes, int n_in,
                              void* d_out, int out_size, void* d_ws, size_t ws_size,
                              hipStream_t stream) {
  const float* x  = (const float*)d_in[0];
  const float* Wq = (const float*)d_in[1];
  const float* bq = (const float*)d_in[2];
  const float* Wk = (const float*)d_in[3];
  const float* bk = (const float*)d_in[4];
  const float* Wv = (const float*)d_in[5];
  const float* bv = (const float*)d_in[6];
  const float* Wo = (const float*)d_in[7];
  const float* bo = (const float*)d_in[8];

  char* ws = (char*)d_ws;
  const size_t MB = 1u << 20;
  bf16* xb  = (bf16*)(ws);               // 16 MB; reused as attn output
  bf16* qB  = (bf16*)(ws + 16 * MB);
  bf16* kB  = (bf16*)(ws + 32 * MB);
  bf16* vtB = (bf16*)(ws + 48 * MB);
  bf16* wqb = (bf16*)(ws + 64 * MB);
  bf16* wkb = (bf16*)(ws + 66 * MB);
  bf16* wvb = (bf16*)(ws + 68 * MB);
  bf16* wob = (bf16*)(ws + 70 * MB);

  cvt_f32_bf16<<<2048, 256, 0, stream>>>(x, xb, (B_N * S_N * D_N) / 4);
  cvt_w4<<<2048, 256, 0, stream>>>(Wq, Wk, Wv, Wo, wqb, wkb, wvb, wob);

  gemm_qkv<<<dim3(24, 32), 512, 0, stream>>>(xb, wqb, wkb, wvb, bq, bk, bv, qB, kB, vtB);

  attn_fwd<<<dim3(1024), 256, 0, stream>>>(qB, kB, vtB, xb);

  gemm_out<<<dim3(8, 32), 512, 0, stream>>>(xb, wob, bo, (float*)d_out);
}